// Round 1
// baseline (3521.583 us; speedup 1.0000x reference)
//
#include <hip/hip_runtime.h>
#include <cstdint>

// ---------------------------------------------------------------------------
// SimpleViT forward on gfx950. bf16 MFMA GEMMs, f32 residual stream.
// R6: QKV/MLP1/MLP2 moved to a 256x256-tile, 8-wave, BK=64 kernel with the
//     8-phase schedule (T3+T4 counted vmcnt, T5 setprio), double-buffered
//     128 KiB LDS, granule-XOR swizzled staging (0 bank conflicts).
//     Old 128x128 kernel kept for embed / Wo / head (short-K or tiny M).
//     MLP2 split-K 4->3 (225-block grid = one clean wave; 3 partials).
// ---------------------------------------------------------------------------

typedef __bf16 bf16_t;
typedef __bf16 bf16x8 __attribute__((ext_vector_type(8)));
typedef __bf16 bf16x4 __attribute__((ext_vector_type(4)));
typedef float  f32x4  __attribute__((ext_vector_type(4)));

#define NLAYER 12
#define BMPAD 56           // M-tiles padded to mult of 8 -> XCD co-location
#define PSTRIDE 4816896l   // elements per partial buffer [6272][768]
#define NBM256 25          // ceil(6272/256)

__device__ __forceinline__ void g2lds16(const void* g, void* l) {
  __builtin_amdgcn_global_load_lds(
      (const __attribute__((address_space(1))) void*)g,
      (__attribute__((address_space(3))) void*)l, 16, 0, 0);
}

// ---------------------------------------------------------------------------
// Weight transpose + f32->bf16: in [R][C] f32 -> out [C][R] bf16 (batched).
// ---------------------------------------------------------------------------
__global__ __launch_bounds__(256) void tcvt(
    const float* __restrict__ in, bf16_t* __restrict__ out,
    int R, int C, long inStride, long outOuter, long outInner, int innerN)
{
  int bi = blockIdx.z;
  in  += (long)bi * inStride;
  out += (long)(bi / innerN) * outOuter + (long)(bi % innerN) * outInner;
  __shared__ float t[32][33];
  int c0 = blockIdx.x * 32, r0 = blockIdx.y * 32;
  int tx = threadIdx.x, ty = threadIdx.y;
  #pragma unroll
  for (int i = ty; i < 32; i += 8) {
    int r = r0 + i, c = c0 + tx;
    if (r < R && c < C) t[i][tx] = in[(long)r * C + c];
  }
  __syncthreads();
  #pragma unroll
  for (int i = ty; i < 32; i += 8) {
    int c = c0 + i, r = r0 + tx;
    if (r < R && c < C) out[(long)c * R + r] = (bf16_t)t[tx][i];
  }
}

// ---------------------------------------------------------------------------
// Patchify: x[32,3,224,224] f32 -> patches[6272,768] bf16
// ---------------------------------------------------------------------------
__global__ __launch_bounds__(256) void patchify(
    const float* __restrict__ x, bf16_t* __restrict__ patches)
{
  int idx = blockIdx.x * 256 + threadIdx.x;
  int bt = idx / 768, pd = idx % 768;
  int b = bt / 196, t = bt % 196;
  int gh = t / 14, gw = t % 14;
  int p1 = pd / 48, rem = pd % 48;
  int p2 = rem / 3, c = rem % 3;
  float v = x[(((long)(b * 3 + c) * 224) + gh * 16 + p1) * 224 + gw * 16 + p2];
  patches[idx] = (bf16_t)v;
}

// ---------------------------------------------------------------------------
// h init: h[b][t][d] = posemb(t,d) + embed_b[d]
// ---------------------------------------------------------------------------
__global__ __launch_bounds__(256) void hinit(
    const float* __restrict__ eb, float* __restrict__ h)
{
  int idx = blockIdx.x * 256 + threadIdx.x;      // 0 .. 196*768-1
  int t = idx / 768, d = idx % 768;
  int gh = t / 14, gw = t % 14;
  int quadrant = d / 192, i = d % 192;
  float omega = powf(10000.0f, -(float)i / 191.0f);
  float arg = (quadrant < 2 ? (float)gw : (float)gh) * omega;
  float pv = ((quadrant & 1) == 0) ? sinf(arg) : cosf(arg);
  float v = pv + eb[d];
  #pragma unroll
  for (int b = 0; b < 32; ++b) h[(long)b * 150528 + idx] = v;
}

// ---------------------------------------------------------------------------
// Fused residual + LayerNorm: h += sum(partials) + bias; xn = LN(h)*g+b.
// ---------------------------------------------------------------------------
__global__ __launch_bounds__(256) void ln_fuse(
    float* __restrict__ h, const bf16_t* __restrict__ pbuf, int nparts,
    const float* __restrict__ bias, const float* __restrict__ g,
    const float* __restrict__ bb, bf16_t* __restrict__ xn)
{
  int row = blockIdx.x * 4 + (threadIdx.x >> 6);
  int lane = threadIdx.x & 63;
  float* hr = h + (long)row * 768;
  const bf16_t* pr = pbuf + (long)row * 768;
  float4 v[3];
  float s = 0.f, s2 = 0.f;
  #pragma unroll
  for (int i = 0; i < 3; ++i) {
    int c4 = lane + 64 * i;
    float4 hv = ((const float4*)hr)[c4];
    float4 acc = {0.f, 0.f, 0.f, 0.f};
    for (int pp = 0; pp < nparts; ++pp) {
      bf16x4 q = *(const bf16x4*)(pr + (long)pp * PSTRIDE + c4 * 4);
      acc.x += (float)q[0]; acc.y += (float)q[1];
      acc.z += (float)q[2]; acc.w += (float)q[3];
    }
    if (bias) {
      float4 bv = ((const float4*)bias)[c4];
      acc.x += bv.x; acc.y += bv.y; acc.z += bv.z; acc.w += bv.w;
    }
    hv.x += acc.x; hv.y += acc.y; hv.z += acc.z; hv.w += acc.w;
    ((float4*)hr)[c4] = hv;
    v[i] = hv;
    s  += hv.x + hv.y + hv.z + hv.w;
    s2 += hv.x * hv.x + hv.y * hv.y + hv.z * hv.z + hv.w * hv.w;
  }
  #pragma unroll
  for (int d = 1; d < 64; d <<= 1) {
    s  += __shfl_xor(s, d, 64);
    s2 += __shfl_xor(s2, d, 64);
  }
  float mu = s * (1.0f / 768.0f);
  float var = s2 * (1.0f / 768.0f) - mu * mu;
  float rs = rsqrtf(var + 1e-5f);
  uint2* outv = (uint2*)(xn + (long)row * 768);
  const float4* gv = (const float4*)g;
  const float4* bv2 = (const float4*)bb;
  #pragma unroll
  for (int i = 0; i < 3; ++i) {
    int c4 = lane + 64 * i;
    float4 gg = gv[c4], b4 = bv2[c4];
    union { bf16_t q[4]; uint2 u; } pk;
    pk.q[0] = (bf16_t)((v[i].x - mu) * rs * gg.x + b4.x);
    pk.q[1] = (bf16_t)((v[i].y - mu) * rs * gg.y + b4.y);
    pk.q[2] = (bf16_t)((v[i].z - mu) * rs * gg.z + b4.z);
    pk.q[3] = (bf16_t)((v[i].w - mu) * rs * gg.w + b4.w);
    outv[c4] = pk.u;
  }
}

// ---------------------------------------------------------------------------
// tanh-form GELU
// ---------------------------------------------------------------------------
__device__ __forceinline__ float gelu_fast(float x) {
  float y = 0.7978845608f * (x + 0.044715f * x * x * x);
  float e = __expf(2.0f * y);
  float t = 1.0f - 2.0f / (e + 1.0f);
  return 0.5f * x * (1.0f + t);
}

// ---------------------------------------------------------------------------
// Old 128x128 GEMM (kept for embed / Wo / head): C[M,N] = A[M,K]*Bt[N,K]^T.
// EPI: 4 = f32 masked (head); 5 = bf16 partial at bout + ks*PSTRIDE.
// ---------------------------------------------------------------------------
template <int EPI, int KTOT, int KS>
__global__ __launch_bounds__(256, 4) void gemm_bt(
    const bf16_t* __restrict__ A, const bf16_t* __restrict__ Bt,
    int ldc, int Mstore, int Nstore,
    const float* __restrict__ bias,
    float* __restrict__ fout, bf16_t* __restrict__ bout)
{
  int lin = blockIdx.x;
  int bm = lin % BMPAD;
  if (bm * 128 >= Mstore) return;
  int rest = lin / BMPAD;
  int ks = rest % KS;
  int bn = rest / KS;
  constexpr int Ksl = KTOT / KS;
  int k0 = ks * Ksl;

  __shared__ __align__(16) bf16_t As[128 * 64];
  __shared__ __align__(16) bf16_t Bs[128 * 64];
  int tid = threadIdx.x;
  int wave = tid >> 6, lane = tid & 63, quad = lane >> 4, l16 = lane & 15;
  int wm = wave >> 1, wn = wave & 1;
  const bf16_t* Ab = A + (long)bm * 128 * KTOT;
  const bf16_t* Bb = Bt + (long)bn * 128 * KTOT;

  f32x4 zero = {0.f, 0.f, 0.f, 0.f};
  f32x4 acc[4][4];
  #pragma unroll
  for (int i = 0; i < 4; ++i)
    #pragma unroll
    for (int j = 0; j < 4; ++j) acc[i][j] = zero;

  int srow = tid >> 3;
  int sgcol = ((tid & 7) ^ (srow & 7)) * 8;
  int ldst = tid * 16;

  int aoff[2][4], boff[2][4];
  #pragma unroll
  for (int kh = 0; kh < 2; ++kh)
    #pragma unroll
    for (int i = 0; i < 4; ++i) {
      int ra = wm * 64 + i * 16 + l16;
      int rb = wn * 64 + i * 16 + l16;
      int pa = ((kh * 4 + quad) ^ (ra & 7)) * 8;
      int pb = ((kh * 4 + quad) ^ (rb & 7)) * 8;
      aoff[kh][i] = ra * 64 + pa;
      boff[kh][i] = rb * 64 + pb;
    }

  for (int kt = k0; kt < k0 + Ksl; kt += 64) {
    __syncthreads();
    #pragma unroll
    for (int c = 0; c < 4; ++c) {
      g2lds16(Ab + (long)(c * 32 + srow) * KTOT + kt + sgcol,
              (char*)As + c * 4096 + ldst);
      g2lds16(Bb + (long)(c * 32 + srow) * KTOT + kt + sgcol,
              (char*)Bs + c * 4096 + ldst);
    }
    __syncthreads();

    #pragma unroll
    for (int kh = 0; kh < 2; ++kh) {
      bf16x8 af[4], bfr[4];
      #pragma unroll
      for (int i = 0; i < 4; ++i) af[i] = *(const bf16x8*)(As + aoff[kh][i]);
      #pragma unroll
      for (int j = 0; j < 4; ++j) bfr[j] = *(const bf16x8*)(Bs + boff[kh][j]);
      #pragma unroll
      for (int i = 0; i < 4; ++i)
        #pragma unroll
        for (int j = 0; j < 4; ++j)
          acc[i][j] = __builtin_amdgcn_mfma_f32_16x16x32_bf16(af[i], bfr[j], acc[i][j], 0, 0, 0);
    }
  }

  int m0 = bm * 128 + wm * 64, n0 = bn * 128 + wn * 64;
  #pragma unroll
  for (int i = 0; i < 4; ++i)
    #pragma unroll
    for (int j = 0; j < 4; ++j)
      #pragma unroll
      for (int r = 0; r < 4; ++r) {
        int row = m0 + i * 16 + quad * 4 + r;
        int col = n0 + j * 16 + l16;
        if (row >= Mstore || col >= Nstore) continue;
        float v = acc[i][j][r];
        if (EPI == 4) {
          fout[(long)row * ldc + col] = v;
        } else {  // EPI 5
          bout[(long)ks * PSTRIDE + (long)row * ldc + col] = (bf16_t)v;
        }
      }
}

// ---------------------------------------------------------------------------
// New 256x256 GEMM, 8 waves (2M x 4N), BK=64, double-buffered LDS (128 KiB),
// 8-phase schedule with counted vmcnt + setprio. Same granule-XOR swizzle:
// physical 16B granule p of row r holds logical granule p^(r&7).
//
// Per iteration (2 K-tiles, even->buf0 odd->buf1), phase p stages one
// half-tile (128 rows, 2 g2lds16/thread):
//   p0: A(2i+1)h0->buf1   p1: A(2i+1)h1->buf1
//   p2: B(2i+2)h0->buf0   p3: B(2i+2)h1->buf0   [tail vmcnt(4)]
//   p4: A(2i+2)h0->buf0   p5: A(2i+2)h1->buf0
//   p6: B(2i+3)h0->buf1   p7: B(2i+3)h1->buf1   [tail vmcnt(4)]
// Tail gates: at p3-tail the newest 4 outstanding loads are p2+p3 (not yet
// needed); everything older (A/B of K-tile 2i+1) must be complete -> buf1
// safe for phases 4-7.  Symmetric at p7-tail for next iteration's buf0.
// Last iteration: p3-tail drains vmcnt(0) (nothing staged at p2/p3).
// EPI: 0 = bf16 store (QKV); 3 = gelu+bias->bf16 (MLP1); 5 = bf16 partial.
// ---------------------------------------------------------------------------
#define VMW(N)                                                     \
  do {                                                             \
    asm volatile("s_waitcnt vmcnt(" #N ")" ::: "memory");          \
    __builtin_amdgcn_sched_barrier(0);                             \
  } while (0)

#define STAGEH(G, L, BUF, H, KT)                                              \
  do {                                                                        \
    g2lds16((G) + (long)((H) * 128 + srow) * KTOT + (KT) + scol,              \
            (char*)(L) + (BUF) * 32768 + (H) * 16384 + ldst);                 \
    g2lds16((G) + (long)((H) * 128 + 64 + srow) * KTOT + (KT) + scol,         \
            (char*)(L) + (BUF) * 32768 + (H) * 16384 + 8192 + ldst);          \
  } while (0)

#define COMPUTE(Q, BUF, STAGEOP, TAILOP)                                      \
  do {                                                                        \
    const char* Ap_ = (const char*)As + (BUF) * 32768 + abase + (Q) * 4096;   \
    const char* Bp_ = (const char*)Bs + (BUF) * 32768 + bbase;                \
    bf16x8 af[2][2];                                                          \
    _Pragma("unroll") for (int ii = 0; ii < 2; ++ii)                          \
      _Pragma("unroll") for (int kh = 0; kh < 2; ++kh)                        \
        af[ii][kh] = *(const bf16x8*)(Ap_ + ii * 2048 + pgo[kh]);             \
    if ((Q) == 0) {                                                           \
      _Pragma("unroll") for (int j = 0; j < 4; ++j)                           \
        _Pragma("unroll") for (int kh = 0; kh < 2; ++kh)                      \
          bfr[j][kh] = *(const bf16x8*)(Bp_ + j * 2048 + pgo[kh]);            \
    }                                                                         \
    STAGEOP;                                                                  \
    __builtin_amdgcn_s_barrier();                                             \
    asm volatile("s_waitcnt lgkmcnt(0)" ::: "memory");                        \
    __builtin_amdgcn_s_setprio(1);                                            \
    _Pragma("unroll") for (int kh = 0; kh < 2; ++kh)                          \
      _Pragma("unroll") for (int ii = 0; ii < 2; ++ii)                        \
        _Pragma("unroll") for (int j = 0; j < 4; ++j)                         \
          acc[2 * (Q) + ii][j] = __builtin_amdgcn_mfma_f32_16x16x32_bf16(     \
              af[ii][kh], bfr[j][kh], acc[2 * (Q) + ii][j], 0, 0, 0);         \
    __builtin_amdgcn_s_setprio(0);                                            \
    TAILOP;                                                                   \
    __builtin_amdgcn_s_barrier();                                             \
  } while (0)

template <int EPI, int KTOT, int KS>
__global__ __launch_bounds__(512, 2) void gemm256(
    const bf16_t* __restrict__ A, const bf16_t* __restrict__ Bt,
    int ldc, int Mstore, const float* __restrict__ bias,
    bf16_t* __restrict__ bout)
{
  constexpr int Ksl = KTOT / KS;
  constexpr int NI  = Ksl / 128;           // iterations, 2 K-tiles each
  int lin = blockIdx.x;
  int bm = lin % NBM256;
  int rest = lin / NBM256;
  int ks = rest % KS;
  int bn = rest / KS;
  int k0 = ks * Ksl;

  __shared__ __align__(16) bf16_t As[2][256 * 64];
  __shared__ __align__(16) bf16_t Bs[2][256 * 64];

  int tid = threadIdx.x;
  int lane = tid & 63, wave = tid >> 6;
  int quad = lane >> 4, l16 = lane & 15;
  int wm = wave >> 2, wn = wave & 3;

  const bf16_t* Ab = A + (long)bm * 256 * KTOT;
  const bf16_t* Bb = Bt + (long)bn * 256 * KTOT;

  // staging: thread covers row (tid>>3) per 64-row call, phys granule tid&7
  int srow = tid >> 3;
  int scol = ((tid & 7) ^ (srow & 7)) * 8;   // source col (elems)
  int ldst = tid * 16;                       // LDS byte offset within call

  // fragment read offsets: row = base + l16 (row&7 == l16&7 always)
  int pgo[2];
  pgo[0] = ((0 * 4 + quad) ^ (l16 & 7)) * 16;
  pgo[1] = ((1 * 4 + quad) ^ (l16 & 7)) * 16;
  int abase = (wm * 128 + l16) * 128;        // bytes
  int bbase = (wn * 64 + l16) * 128;

  f32x4 acc[8][4];
  f32x4 zero = {0.f, 0.f, 0.f, 0.f};
  #pragma unroll
  for (int i = 0; i < 8; ++i)
    #pragma unroll
    for (int j = 0; j < 4; ++j) acc[i][j] = zero;
  bf16x8 bfr[4][2];

  // prologue: K-tile 0 (A+B) + K-tile 1 (B) = 12 loads; gate K-tile 0.
  STAGEH(Ab, As, 0, 0, k0);
  STAGEH(Ab, As, 0, 1, k0);
  STAGEH(Bb, Bs, 0, 0, k0);
  STAGEH(Bb, Bs, 0, 1, k0);
  STAGEH(Bb, Bs, 1, 0, k0 + 64);
  STAGEH(Bb, Bs, 1, 1, k0 + 64);
  VMW(4);
  __builtin_amdgcn_s_barrier();

  #pragma unroll 1
  for (int i = 0; i < NI; ++i) {
    int kb = k0 + i * 128;
    bool nl = (i + 1 < NI);
    COMPUTE(0, 0, STAGEH(Ab, As, 1, 0, kb + 64), (void)0);
    COMPUTE(1, 0, STAGEH(Ab, As, 1, 1, kb + 64), (void)0);
    COMPUTE(2, 0, { if (nl) STAGEH(Bb, Bs, 0, 0, kb + 128); }, (void)0);
    COMPUTE(3, 0, { if (nl) STAGEH(Bb, Bs, 0, 1, kb + 128); },
            { if (nl) VMW(4); else VMW(0); });
    COMPUTE(0, 1, { if (nl) STAGEH(Ab, As, 0, 0, kb + 128); }, (void)0);
    COMPUTE(1, 1, { if (nl) STAGEH(Ab, As, 0, 1, kb + 128); }, (void)0);
    COMPUTE(2, 1, { if (nl) STAGEH(Bb, Bs, 1, 0, kb + 192); }, (void)0);
    COMPUTE(3, 1, { if (nl) STAGEH(Bb, Bs, 1, 1, kb + 192); },
            { if (nl) VMW(4); });
  }

  int m0 = bm * 256 + wm * 128, n0 = bn * 256 + wn * 64;
  #pragma unroll
  for (int i = 0; i < 8; ++i)
    #pragma unroll
    for (int j = 0; j < 4; ++j)
      #pragma unroll
      for (int r = 0; r < 4; ++r) {
        int row = m0 + i * 16 + quad * 4 + r;
        if (row >= Mstore) continue;
        int col = n0 + j * 16 + l16;
        float v = acc[i][j][r];
        if (EPI == 3) {
          bout[(long)row * ldc + col] = (bf16_t)gelu_fast(v + bias[col]);
        } else if (EPI == 5) {
          bout[(long)ks * PSTRIDE + (long)row * ldc + col] = (bf16_t)v;
        } else {  // EPI 0
          bout[(long)row * ldc + col] = (bf16_t)v;
        }
      }
}

// ---------------------------------------------------------------------------
// V transpose: qkv v-part -> Vt[bh][64][224] bf16, cols s>=196 zero-filled.
// ---------------------------------------------------------------------------
__global__ __launch_bounds__(256) void vtrans(
    const bf16_t* __restrict__ qkv, bf16_t* __restrict__ Vt)
{
  int bh = blockIdx.z, b = bh / 12, h = bh % 12;
  __shared__ bf16_t t[32][33];
  int e0 = blockIdx.x * 32, s0 = blockIdx.y * 32;
  int tx = threadIdx.x, ty = threadIdx.y;
  #pragma unroll
  for (int i = ty; i < 32; i += 8) {
    int s = s0 + i;
    bf16_t v = (bf16_t)0.0f;
    if (s < 196) v = qkv[(long)(b * 196 + s) * 2304 + 1536 + h * 64 + e0 + tx];
    t[i][tx] = v;
  }
  __syncthreads();
  #pragma unroll
  for (int i = ty; i < 32; i += 8) {
    int e = e0 + i, s = s0 + tx;
    if (s < 224) Vt[(long)bh * 64 * 224 + (long)e * 224 + s] = t[tx][i];
  }
}

// ---------------------------------------------------------------------------
// Fused attention: scores -> softmax -> P in LDS -> P@V -> att.
// ---------------------------------------------------------------------------
__global__ __launch_bounds__(64) void attn_fused(
    const bf16_t* __restrict__ qkv, const bf16_t* __restrict__ Vt,
    bf16_t* __restrict__ att)
{
  __shared__ __align__(16) bf16_t Pl[16 * 232];
  int mt = blockIdx.x, bh = blockIdx.y;
  int b = bh / 12, h = bh % 12;
  int lane = threadIdx.x, quad = lane >> 4, l16 = lane & 15;

  #pragma unroll
  for (int i = 0; i < 4; ++i) {
    int idx = lane + 64 * i;
    Pl[(idx >> 4) * 232 + 208 + (idx & 15)] = (bf16_t)0.0f;
  }

  f32x4 zero = {0.f, 0.f, 0.f, 0.f};
  f32x4 acc[13];
  #pragma unroll
  for (int nt = 0; nt < 13; ++nt) acc[nt] = zero;

  long qoff = (long)(b * 196 + mt * 16 + l16) * 2304 + h * 64;
  #pragma unroll
  for (int kk = 0; kk < 2; ++kk) {
    bf16x8 a = *(const bf16x8*)(qkv + qoff + kk * 32 + quad * 8);
    #pragma unroll
    for (int nt = 0; nt < 13; ++nt) {
      long koff = (long)(b * 196 + nt * 16 + l16) * 2304 + 768 + h * 64 + kk * 32 + quad * 8;
      bf16x8 bb = *(const bf16x8*)(qkv + koff);
      acc[nt] = __builtin_amdgcn_mfma_f32_16x16x32_bf16(a, bb, acc[nt], 0, 0, 0);
    }
  }

  float p[13][4];
  #pragma unroll
  for (int nt = 0; nt < 13; ++nt)
    #pragma unroll
    for (int r = 0; r < 4; ++r) {
      float v = acc[nt][r] * 0.125f;
      if (nt == 12 && l16 >= 4) v = -1e30f;
      p[nt][r] = v;
    }

  #pragma unroll
  for (int r = 0; r < 4; ++r) {
    float mx = -1e30f;
    #pragma unroll
    for (int nt = 0; nt < 13; ++nt) mx = fmaxf(mx, p[nt][r]);
    #pragma unroll
    for (int d = 1; d < 16; d <<= 1) mx = fmaxf(mx, __shfl_xor(mx, d, 64));
    float sm = 0.f;
    #pragma unroll
    for (int nt = 0; nt < 13; ++nt) {
      float e = __expf(p[nt][r] - mx);
      p[nt][r] = e;
      sm += e;
    }
    #pragma unroll
    for (int d = 1; d < 16; d <<= 1) sm += __shfl_xor(sm, d, 64);
    float inv = 1.0f / sm;
    #pragma unroll
    for (int nt = 0; nt < 13; ++nt) p[nt][r] *= inv;
  }

  #pragma unroll
  for (int nt = 0; nt < 13; ++nt)
    #pragma unroll
    for (int r = 0; r < 4; ++r)
      Pl[(quad * 4 + r) * 232 + nt * 16 + l16] = (bf16_t)p[nt][r];
  __syncthreads();

  f32x4 pv[4];
  #pragma unroll
  for (int nt = 0; nt < 4; ++nt) pv[nt] = zero;
  const bf16_t* Vb = Vt + (long)bh * 64 * 224;
  #pragma unroll
  for (int ks = 0; ks < 7; ++ks) {
    bf16x8 a = *(const bf16x8*)(Pl + l16 * 232 + ks * 32 + quad * 8);
    #pragma unroll
    for (int nt = 0; nt < 4; ++nt) {
      bf16x8 bb = *(const bf16x8*)(Vb + (long)(nt * 16 + l16) * 224 + ks * 32 + quad * 8);
      pv[nt] = __builtin_amdgcn_mfma_f32_16x16x32_bf16(a, bb, pv[nt], 0, 0, 0);
    }
  }

  #pragma unroll
  for (int nt = 0; nt < 4; ++nt)
    #pragma unroll
    for (int r = 0; r < 4; ++r) {
      int t = mt * 16 + quad * 4 + r;
      if (t < 196)
        att[(long)(b * 196 + t) * 768 + h * 64 + nt * 16 + l16] = (bf16_t)pv[nt][r];
    }
}

// ---------------------------------------------------------------------------
// Mean pool + final MLP2 partial reduction (3 partials) + bias
// ---------------------------------------------------------------------------
__global__ __launch_bounds__(256) void meanpool_fuse(
    const float* __restrict__ h, const bf16_t* __restrict__ pbuf,
    const float* __restrict__ bias, bf16_t* __restrict__ hm)
{
  int d = blockIdx.y * 256 + threadIdx.x;
  int b = blockIdx.x;
  float s = 0.f;
  for (int t = 0; t < 196; ++t) {
    long idx = (long)(b * 196 + t) * 768 + d;
    float v = h[idx];
    #pragma unroll
    for (int pp = 0; pp < 3; ++pp) v += (float)pbuf[idx + pp * PSTRIDE];
    s += v;
  }
  hm[b * 768 + d] = (bf16_t)(s * (1.0f / 196.0f) + bias[d]);
}

// ---------------------------------------------------------------------------
// Host launch
// ---------------------------------------------------------------------------
extern "C" void kernel_launch(void* const* d_in, const int* in_sizes, int n_in,
                              void* d_out, int out_size, void* d_ws, size_t ws_size,
                              hipStream_t stream)
{
  const float* x       = (const float*)d_in[0];
  const float* embed_W = (const float*)d_in[1];
  const float* embed_b = (const float*)d_in[2];
  const float* Wq      = (const float*)d_in[3];
  const float* Wk      = (const float*)d_in[4];
  const float* Wv      = (const float*)d_in[5];
  const float* Wo      = (const float*)d_in[6];
  const float* bo      = (const float*)d_in[7];
  const float* ln1_g   = (const float*)d_in[8];
  const float* ln1_b   = (const float*)d_in[9];
  const float* ln2_g   = (const float*)d_in[10];
  const float* ln2_b   = (const float*)d_in[11];
  const float* W1      = (const float*)d_in[12];
  const float* b1      = (const float*)d_in[13];
  const float* W2      = (const float*)d_in[14];
  const float* b2      = (const float*)d_in[15];
  const float* head_W  = (const float*)d_in[16];

  char* p = (char*)d_ws;
  auto carve = [&](size_t bytes) {
    char* r = p;
    p += (bytes + 255) & ~(size_t)255;
    return r;
  };
  bf16_t* embed_Wt = (bf16_t*)carve(589824ull * 2);
  bf16_t* qkvT     = (bf16_t*)carve(21233664ull * 2);
  bf16_t* WoT      = (bf16_t*)carve(7077888ull * 2);
  bf16_t* W1T      = (bf16_t*)carve(28311552ull * 2);
  bf16_t* W2T      = (bf16_t*)carve(28311552ull * 2);
  bf16_t* headWt   = (bf16_t*)carve(786432ull * 2);
  bf16_t* patches  = (bf16_t*)carve(4816896ull * 2);
  float*  h        = (float*)carve(4816896ull * 4);
  bf16_t* xn       = (bf16_t*)carve(4816896ull * 2);
  bf16_t* qkv      = (bf16_t*)carve(14487552ull * 2);
  bf16_t* Vt       = (bf16_t*)carve(5505024ull * 2);
  bf16_t* hmlp     = (bf16_t*)carve(19267584ull * 2);
  bf16_t* att      = (bf16_t*)carve(4816896ull * 2);
  bf16_t* pbuf     = (bf16_t*)carve(4ull * PSTRIDE * 2);
  bf16_t* hm       = (bf16_t*)carve(98304ull * 2);
  (void)ws_size; (void)n_in; (void)in_sizes; (void)out_size;

  dim3 tb32(32, 8);

  tcvt<<<dim3(24, 24, 1),   tb32, 0, stream>>>(embed_W, embed_Wt, 768, 768, 0, 0, 0, 1);
  tcvt<<<dim3(24, 24, 12),  tb32, 0, stream>>>(Wo, WoT, 768, 768, 589824, 589824, 0, 1);
  tcvt<<<dim3(2, 24, 144),  tb32, 0, stream>>>(Wq, qkvT,           768, 64, 49152, 1769472, 49152, 12);
  tcvt<<<dim3(2, 24, 144),  tb32, 0, stream>>>(Wk, qkvT + 589824,  768, 64, 49152, 1769472, 49152, 12);
  tcvt<<<dim3(2, 24, 144),  tb32, 0, stream>>>(Wv, qkvT + 1179648, 768, 64, 49152, 1769472, 49152, 12);
  tcvt<<<dim3(96, 24, 12),  tb32, 0, stream>>>(W1, W1T, 768, 3072, 2359296, 2359296, 0, 1);
  tcvt<<<dim3(24, 96, 12),  tb32, 0, stream>>>(W2, W2T, 3072, 768, 2359296, 2359296, 0, 1);
  tcvt<<<dim3(32, 24, 1),   tb32, 0, stream>>>(head_W, headWt, 768, 1000, 0, 0, 0, 1);

  patchify<<<18816, 256, 0, stream>>>(x, patches);
  hinit<<<588, 256, 0, stream>>>(embed_b, h);

  gemm_bt<5, 768, 2><<<BMPAD * 6 * 2, 256, 0, stream>>>(
      patches, embed_Wt, 768, 6272, 768, nullptr, nullptr, pbuf);

  for (int l = 0; l < NLAYER; ++l) {
    ln_fuse<<<1568, 256, 0, stream>>>(
        h, pbuf, l == 0 ? 2 : 3, l == 0 ? nullptr : b2 + (l - 1) * 768,
        ln1_g + l * 768, ln1_b + l * 768, xn);
    gemm256<0, 768, 1><<<NBM256 * 9, 512, 0, stream>>>(
        xn, qkvT + (long)l * 1769472, 2304, 6272, nullptr, qkv);
    vtrans<<<dim3(2, 7, 384), tb32, 0, stream>>>(qkv, Vt);
    attn_fused<<<dim3(13, 384), 64, 0, stream>>>(qkv, Vt, att);
    gemm_bt<5, 768, 2><<<BMPAD * 6 * 2, 256, 0, stream>>>(
        att, WoT + (long)l * 589824, 768, 6272, 768,
        nullptr, nullptr, pbuf);
    ln_fuse<<<1568, 256, 0, stream>>>(
        h, pbuf, 2, bo + l * 768, ln2_g + l * 768, ln2_b + l * 768, xn);
    gemm256<3, 768, 1><<<NBM256 * 12, 512, 0, stream>>>(
        xn, W1T + (long)l * 2359296, 3072, 6272, b1 + l * 3072, hmlp);
    gemm256<5, 3072, 3><<<NBM256 * 3 * 3, 512, 0, stream>>>(
        hmlp, W2T + (long)l * 2359296, 768, 6272, nullptr, pbuf);
  }

  meanpool_fuse<<<dim3(32, 3), 256, 0, stream>>>(h, pbuf, b2 + 11 * 768, hm);
  gemm_bt<4, 768, 1><<<BMPAD * 8, 256, 0, stream>>>(
      hm, headWt, 1000, 32, 1000, nullptr, (float*)d_out, nullptr);
}

// Round 2
// 3109.585 us; speedup vs baseline: 1.1325x; 1.1325x over previous
//
#include <hip/hip_runtime.h>
#include <cstdint>

// ---------------------------------------------------------------------------
// SimpleViT forward on gfx950. bf16 MFMA GEMMs, f32 residual stream.
// R7: hybrid. gemm256 (256x256 8-phase, counted vmcnt, setprio) kept ONLY
//     where it measured a win (QKV, MLP2: 225-block grids = one clean
//     dispatch wave), now with m204-bijective chunked XCD swizzle so each
//     XCD owns a contiguous (bm-major) chunk -> A panels fetched ~once per
//     owning XCD instead of everywhere (R6 FETCH 66.7MB, 2.3x over-fetch).
//     MLP1 (300 blocks -> 2-wave quantization at 1 block/CU) reverted to
//     the measured-71us 128x128 gemm_bt. embed/Wo/head stay on gemm_bt.
// ---------------------------------------------------------------------------

typedef __bf16 bf16_t;
typedef __bf16 bf16x8 __attribute__((ext_vector_type(8)));
typedef __bf16 bf16x4 __attribute__((ext_vector_type(4)));
typedef float  f32x4  __attribute__((ext_vector_type(4)));

#define NLAYER 12
#define BMPAD 56           // M-tiles padded to mult of 8 -> XCD co-location
#define PSTRIDE 4816896l   // elements per partial buffer [6272][768]
#define NBM256 25          // ceil(6272/256)

__device__ __forceinline__ void g2lds16(const void* g, void* l) {
  __builtin_amdgcn_global_load_lds(
      (const __attribute__((address_space(1))) void*)g,
      (__attribute__((address_space(3))) void*)l, 16, 0, 0);
}

// ---------------------------------------------------------------------------
// Weight transpose + f32->bf16: in [R][C] f32 -> out [C][R] bf16 (batched).
// ---------------------------------------------------------------------------
__global__ __launch_bounds__(256) void tcvt(
    const float* __restrict__ in, bf16_t* __restrict__ out,
    int R, int C, long inStride, long outOuter, long outInner, int innerN)
{
  int bi = blockIdx.z;
  in  += (long)bi * inStride;
  out += (long)(bi / innerN) * outOuter + (long)(bi % innerN) * outInner;
  __shared__ float t[32][33];
  int c0 = blockIdx.x * 32, r0 = blockIdx.y * 32;
  int tx = threadIdx.x, ty = threadIdx.y;
  #pragma unroll
  for (int i = ty; i < 32; i += 8) {
    int r = r0 + i, c = c0 + tx;
    if (r < R && c < C) t[i][tx] = in[(long)r * C + c];
  }
  __syncthreads();
  #pragma unroll
  for (int i = ty; i < 32; i += 8) {
    int c = c0 + i, r = r0 + tx;
    if (r < R && c < C) out[(long)c * R + r] = (bf16_t)t[tx][i];
  }
}

// ---------------------------------------------------------------------------
// Patchify: x[32,3,224,224] f32 -> patches[6272,768] bf16
// ---------------------------------------------------------------------------
__global__ __launch_bounds__(256) void patchify(
    const float* __restrict__ x, bf16_t* __restrict__ patches)
{
  int idx = blockIdx.x * 256 + threadIdx.x;
  int bt = idx / 768, pd = idx % 768;
  int b = bt / 196, t = bt % 196;
  int gh = t / 14, gw = t % 14;
  int p1 = pd / 48, rem = pd % 48;
  int p2 = rem / 3, c = rem % 3;
  float v = x[(((long)(b * 3 + c) * 224) + gh * 16 + p1) * 224 + gw * 16 + p2];
  patches[idx] = (bf16_t)v;
}

// ---------------------------------------------------------------------------
// h init: h[b][t][d] = posemb(t,d) + embed_b[d]
// ---------------------------------------------------------------------------
__global__ __launch_bounds__(256) void hinit(
    const float* __restrict__ eb, float* __restrict__ h)
{
  int idx = blockIdx.x * 256 + threadIdx.x;      // 0 .. 196*768-1
  int t = idx / 768, d = idx % 768;
  int gh = t / 14, gw = t % 14;
  int quadrant = d / 192, i = d % 192;
  float omega = powf(10000.0f, -(float)i / 191.0f);
  float arg = (quadrant < 2 ? (float)gw : (float)gh) * omega;
  float pv = ((quadrant & 1) == 0) ? sinf(arg) : cosf(arg);
  float v = pv + eb[d];
  #pragma unroll
  for (int b = 0; b < 32; ++b) h[(long)b * 150528 + idx] = v;
}

// ---------------------------------------------------------------------------
// Fused residual + LayerNorm: h += sum(partials) + bias; xn = LN(h)*g+b.
// ---------------------------------------------------------------------------
__global__ __launch_bounds__(256) void ln_fuse(
    float* __restrict__ h, const bf16_t* __restrict__ pbuf, int nparts,
    const float* __restrict__ bias, const float* __restrict__ g,
    const float* __restrict__ bb, bf16_t* __restrict__ xn)
{
  int row = blockIdx.x * 4 + (threadIdx.x >> 6);
  int lane = threadIdx.x & 63;
  float* hr = h + (long)row * 768;
  const bf16_t* pr = pbuf + (long)row * 768;
  float4 v[3];
  float s = 0.f, s2 = 0.f;
  #pragma unroll
  for (int i = 0; i < 3; ++i) {
    int c4 = lane + 64 * i;
    float4 hv = ((const float4*)hr)[c4];
    float4 acc = {0.f, 0.f, 0.f, 0.f};
    for (int pp = 0; pp < nparts; ++pp) {
      bf16x4 q = *(const bf16x4*)(pr + (long)pp * PSTRIDE + c4 * 4);
      acc.x += (float)q[0]; acc.y += (float)q[1];
      acc.z += (float)q[2]; acc.w += (float)q[3];
    }
    if (bias) {
      float4 bv = ((const float4*)bias)[c4];
      acc.x += bv.x; acc.y += bv.y; acc.z += bv.z; acc.w += bv.w;
    }
    hv.x += acc.x; hv.y += acc.y; hv.z += acc.z; hv.w += acc.w;
    ((float4*)hr)[c4] = hv;
    v[i] = hv;
    s  += hv.x + hv.y + hv.z + hv.w;
    s2 += hv.x * hv.x + hv.y * hv.y + hv.z * hv.z + hv.w * hv.w;
  }
  #pragma unroll
  for (int d = 1; d < 64; d <<= 1) {
    s  += __shfl_xor(s, d, 64);
    s2 += __shfl_xor(s2, d, 64);
  }
  float mu = s * (1.0f / 768.0f);
  float var = s2 * (1.0f / 768.0f) - mu * mu;
  float rs = rsqrtf(var + 1e-5f);
  uint2* outv = (uint2*)(xn + (long)row * 768);
  const float4* gv = (const float4*)g;
  const float4* bv2 = (const float4*)bb;
  #pragma unroll
  for (int i = 0; i < 3; ++i) {
    int c4 = lane + 64 * i;
    float4 gg = gv[c4], b4 = bv2[c4];
    union { bf16_t q[4]; uint2 u; } pk;
    pk.q[0] = (bf16_t)((v[i].x - mu) * rs * gg.x + b4.x);
    pk.q[1] = (bf16_t)((v[i].y - mu) * rs * gg.y + b4.y);
    pk.q[2] = (bf16_t)((v[i].z - mu) * rs * gg.z + b4.z);
    pk.q[3] = (bf16_t)((v[i].w - mu) * rs * gg.w + b4.w);
    outv[c4] = pk.u;
  }
}

// ---------------------------------------------------------------------------
// tanh-form GELU
// ---------------------------------------------------------------------------
__device__ __forceinline__ float gelu_fast(float x) {
  float y = 0.7978845608f * (x + 0.044715f * x * x * x);
  float e = __expf(2.0f * y);
  float t = 1.0f - 2.0f / (e + 1.0f);
  return 0.5f * x * (1.0f + t);
}

// ---------------------------------------------------------------------------
// 128x128 GEMM (embed / Wo / MLP1 / head): C[M,N] = A[M,K]*Bt[N,K]^T.
// BK=64, 4 waves, 4 blocks/CU, XOR-swizzled staging, bm->XCD co-location.
// EPI: 3 = gelu+bias->bf16 (MLP1); 4 = f32 masked (head);
//      5 = bf16 partial at bout + ks*PSTRIDE (embed/Wo).
// ---------------------------------------------------------------------------
template <int EPI, int KTOT, int KS>
__global__ __launch_bounds__(256, 4) void gemm_bt(
    const bf16_t* __restrict__ A, const bf16_t* __restrict__ Bt,
    int ldc, int Mstore, int Nstore,
    const float* __restrict__ bias,
    float* __restrict__ fout, bf16_t* __restrict__ bout)
{
  int lin = blockIdx.x;
  int bm = lin % BMPAD;
  if (bm * 128 >= Mstore) return;
  int rest = lin / BMPAD;
  int ks = rest % KS;
  int bn = rest / KS;
  constexpr int Ksl = KTOT / KS;
  int k0 = ks * Ksl;

  __shared__ __align__(16) bf16_t As[128 * 64];
  __shared__ __align__(16) bf16_t Bs[128 * 64];
  int tid = threadIdx.x;
  int wave = tid >> 6, lane = tid & 63, quad = lane >> 4, l16 = lane & 15;
  int wm = wave >> 1, wn = wave & 1;
  const bf16_t* Ab = A + (long)bm * 128 * KTOT;
  const bf16_t* Bb = Bt + (long)bn * 128 * KTOT;

  f32x4 zero = {0.f, 0.f, 0.f, 0.f};
  f32x4 acc[4][4];
  #pragma unroll
  for (int i = 0; i < 4; ++i)
    #pragma unroll
    for (int j = 0; j < 4; ++j) acc[i][j] = zero;

  int srow = tid >> 3;
  int sgcol = ((tid & 7) ^ (srow & 7)) * 8;
  int ldst = tid * 16;

  int aoff[2][4], boff[2][4];
  #pragma unroll
  for (int kh = 0; kh < 2; ++kh)
    #pragma unroll
    for (int i = 0; i < 4; ++i) {
      int ra = wm * 64 + i * 16 + l16;
      int rb = wn * 64 + i * 16 + l16;
      int pa = ((kh * 4 + quad) ^ (ra & 7)) * 8;
      int pb = ((kh * 4 + quad) ^ (rb & 7)) * 8;
      aoff[kh][i] = ra * 64 + pa;
      boff[kh][i] = rb * 64 + pb;
    }

  for (int kt = k0; kt < k0 + Ksl; kt += 64) {
    __syncthreads();
    #pragma unroll
    for (int c = 0; c < 4; ++c) {
      g2lds16(Ab + (long)(c * 32 + srow) * KTOT + kt + sgcol,
              (char*)As + c * 4096 + ldst);
      g2lds16(Bb + (long)(c * 32 + srow) * KTOT + kt + sgcol,
              (char*)Bs + c * 4096 + ldst);
    }
    __syncthreads();

    #pragma unroll
    for (int kh = 0; kh < 2; ++kh) {
      bf16x8 af[4], bfr[4];
      #pragma unroll
      for (int i = 0; i < 4; ++i) af[i] = *(const bf16x8*)(As + aoff[kh][i]);
      #pragma unroll
      for (int j = 0; j < 4; ++j) bfr[j] = *(const bf16x8*)(Bs + boff[kh][j]);
      #pragma unroll
      for (int i = 0; i < 4; ++i)
        #pragma unroll
        for (int j = 0; j < 4; ++j)
          acc[i][j] = __builtin_amdgcn_mfma_f32_16x16x32_bf16(af[i], bfr[j], acc[i][j], 0, 0, 0);
    }
  }

  int m0 = bm * 128 + wm * 64, n0 = bn * 128 + wn * 64;
  #pragma unroll
  for (int i = 0; i < 4; ++i)
    #pragma unroll
    for (int j = 0; j < 4; ++j)
      #pragma unroll
      for (int r = 0; r < 4; ++r) {
        int row = m0 + i * 16 + quad * 4 + r;
        int col = n0 + j * 16 + l16;
        if (row >= Mstore || col >= Nstore) continue;
        float v = acc[i][j][r];
        if (EPI == 3) {
          bout[(long)row * ldc + col] = (bf16_t)gelu_fast(v + bias[col]);
        } else if (EPI == 4) {
          fout[(long)row * ldc + col] = v;
        } else {  // EPI 5
          bout[(long)ks * PSTRIDE + (long)row * ldc + col] = (bf16_t)v;
        }
      }
}

// ---------------------------------------------------------------------------
// 256x256 GEMM, 8 waves (2M x 4N), BK=64, double-buffered LDS (128 KiB),
// 8-phase schedule with counted vmcnt + setprio. Granule-XOR swizzle:
// physical 16B granule p of row r holds logical granule p^(r&7).
// m204-bijective chunked XCD swizzle: launched bid -> (xcd=bid%8, idx),
// each XCD covers a contiguous logical chunk; logical is bm-major so an
// XCD's ~28-block chunk = ~3 bm x all (bn,ks) -> A panels fetched once per
// owning XCD, B streams once per XCD.
// EPI: 0 = bf16 store (QKV); 5 = bf16 partial at bout + ks*PSTRIDE (MLP2).
// ---------------------------------------------------------------------------
#define VMW(N)                                                     \
  do {                                                             \
    asm volatile("s_waitcnt vmcnt(" #N ")" ::: "memory");          \
    __builtin_amdgcn_sched_barrier(0);                             \
  } while (0)

#define STAGEH(G, L, BUF, H, KT)                                              \
  do {                                                                        \
    g2lds16((G) + (long)((H) * 128 + srow) * KTOT + (KT) + scol,              \
            (char*)(L) + (BUF) * 32768 + (H) * 16384 + ldst);                 \
    g2lds16((G) + (long)((H) * 128 + 64 + srow) * KTOT + (KT) + scol,         \
            (char*)(L) + (BUF) * 32768 + (H) * 16384 + 8192 + ldst);          \
  } while (0)

#define COMPUTE(Q, BUF, STAGEOP, TAILOP)                                      \
  do {                                                                        \
    const char* Ap_ = (const char*)As + (BUF) * 32768 + abase + (Q) * 4096;   \
    const char* Bp_ = (const char*)Bs + (BUF) * 32768 + bbase;                \
    bf16x8 af[2][2];                                                          \
    _Pragma("unroll") for (int ii = 0; ii < 2; ++ii)                          \
      _Pragma("unroll") for (int kh = 0; kh < 2; ++kh)                        \
        af[ii][kh] = *(const bf16x8*)(Ap_ + ii * 2048 + pgo[kh]);             \
    if ((Q) == 0) {                                                           \
      _Pragma("unroll") for (int j = 0; j < 4; ++j)                           \
        _Pragma("unroll") for (int kh = 0; kh < 2; ++kh)                      \
          bfr[j][kh] = *(const bf16x8*)(Bp_ + j * 2048 + pgo[kh]);            \
    }                                                                         \
    STAGEOP;                                                                  \
    __builtin_amdgcn_s_barrier();                                             \
    asm volatile("s_waitcnt lgkmcnt(0)" ::: "memory");                        \
    __builtin_amdgcn_s_setprio(1);                                            \
    _Pragma("unroll") for (int kh = 0; kh < 2; ++kh)                          \
      _Pragma("unroll") for (int ii = 0; ii < 2; ++ii)                        \
        _Pragma("unroll") for (int j = 0; j < 4; ++j)                         \
          acc[2 * (Q) + ii][j] = __builtin_amdgcn_mfma_f32_16x16x32_bf16(     \
              af[ii][kh], bfr[j][kh], acc[2 * (Q) + ii][j], 0, 0, 0);         \
    __builtin_amdgcn_s_setprio(0);                                            \
    TAILOP;                                                                   \
    __builtin_amdgcn_s_barrier();                                             \
  } while (0)

template <int EPI, int KTOT, int KS, int NBNKS>
__global__ __launch_bounds__(512, 2) void gemm256(
    const bf16_t* __restrict__ A, const bf16_t* __restrict__ Bt,
    int ldc, int Mstore, const float* __restrict__ bias,
    bf16_t* __restrict__ bout)
{
  constexpr int Ksl = KTOT / KS;
  constexpr int NI  = Ksl / 128;           // iterations, 2 K-tiles each
  // bijective chunked XCD swizzle (m204): xcd = bid%8 owns a contiguous
  // logical chunk of size q or q+1.
  constexpr int nwgc = NBM256 * NBNKS;
  constexpr int cq = nwgc / 8, cr = nwgc % 8;
  int bid = blockIdx.x;
  int xcd = bid & 7, idx = bid >> 3;
  int logical = (xcd < cr ? xcd * (cq + 1) : cr * (cq + 1) + (xcd - cr) * cq) + idx;
  int bm = logical / NBNKS;                // bm-major: chunk = few bm, all bn/ks
  int rest = logical - bm * NBNKS;
  int ks = rest % KS;
  int bn = rest / KS;
  int k0 = ks * Ksl;

  __shared__ __align__(16) bf16_t As[2][256 * 64];
  __shared__ __align__(16) bf16_t Bs[2][256 * 64];

  int tid = threadIdx.x;
  int lane = tid & 63, wave = tid >> 6;
  int quad = lane >> 4, l16 = lane & 15;
  int wm = wave >> 2, wn = wave & 3;

  const bf16_t* Ab = A + (long)bm * 256 * KTOT;
  const bf16_t* Bb = Bt + (long)bn * 256 * KTOT;

  // staging: thread covers row (tid>>3) per 64-row call, phys granule tid&7
  int srow = tid >> 3;
  int scol = ((tid & 7) ^ (srow & 7)) * 8;   // source col (elems)
  int ldst = tid * 16;                       // LDS byte offset within call

  // fragment read offsets: row = base + l16 (row&7 == l16&7 always)
  int pgo[2];
  pgo[0] = ((0 * 4 + quad) ^ (l16 & 7)) * 16;
  pgo[1] = ((1 * 4 + quad) ^ (l16 & 7)) * 16;
  int abase = (wm * 128 + l16) * 128;        // bytes
  int bbase = (wn * 64 + l16) * 128;

  f32x4 acc[8][4];
  f32x4 zero = {0.f, 0.f, 0.f, 0.f};
  #pragma unroll
  for (int i = 0; i < 8; ++i)
    #pragma unroll
    for (int j = 0; j < 4; ++j) acc[i][j] = zero;
  bf16x8 bfr[4][2];

  // prologue: K-tile 0 (A+B) + K-tile 1 (B) = 12 loads; gate K-tile 0.
  STAGEH(Ab, As, 0, 0, k0);
  STAGEH(Ab, As, 0, 1, k0);
  STAGEH(Bb, Bs, 0, 0, k0);
  STAGEH(Bb, Bs, 0, 1, k0);
  STAGEH(Bb, Bs, 1, 0, k0 + 64);
  STAGEH(Bb, Bs, 1, 1, k0 + 64);
  VMW(4);
  __builtin_amdgcn_s_barrier();

  #pragma unroll 1
  for (int i = 0; i < NI; ++i) {
    int kb = k0 + i * 128;
    bool nl = (i + 1 < NI);
    COMPUTE(0, 0, STAGEH(Ab, As, 1, 0, kb + 64), (void)0);
    COMPUTE(1, 0, STAGEH(Ab, As, 1, 1, kb + 64), (void)0);
    COMPUTE(2, 0, { if (nl) STAGEH(Bb, Bs, 0, 0, kb + 128); }, (void)0);
    COMPUTE(3, 0, { if (nl) STAGEH(Bb, Bs, 0, 1, kb + 128); },
            { if (nl) VMW(4); else VMW(0); });
    COMPUTE(0, 1, { if (nl) STAGEH(Ab, As, 0, 0, kb + 128); }, (void)0);
    COMPUTE(1, 1, { if (nl) STAGEH(Ab, As, 0, 1, kb + 128); }, (void)0);
    COMPUTE(2, 1, { if (nl) STAGEH(Bb, Bs, 1, 0, kb + 192); }, (void)0);
    COMPUTE(3, 1, { if (nl) STAGEH(Bb, Bs, 1, 1, kb + 192); },
            { if (nl) VMW(4); });
  }

  int m0 = bm * 256 + wm * 128, n0 = bn * 256 + wn * 64;
  #pragma unroll
  for (int i = 0; i < 8; ++i)
    #pragma unroll
    for (int j = 0; j < 4; ++j)
      #pragma unroll
      for (int r = 0; r < 4; ++r) {
        int row = m0 + i * 16 + quad * 4 + r;
        if (row >= Mstore) continue;
        int col = n0 + j * 16 + l16;
        float v = acc[i][j][r];
        if (EPI == 5) {
          bout[(long)ks * PSTRIDE + (long)row * ldc + col] = (bf16_t)v;
        } else {  // EPI 0
          bout[(long)row * ldc + col] = (bf16_t)v;
        }
      }
}

// ---------------------------------------------------------------------------
// V transpose: qkv v-part -> Vt[bh][64][224] bf16, cols s>=196 zero-filled.
// ---------------------------------------------------------------------------
__global__ __launch_bounds__(256) void vtrans(
    const bf16_t* __restrict__ qkv, bf16_t* __restrict__ Vt)
{
  int bh = blockIdx.z, b = bh / 12, h = bh % 12;
  __shared__ bf16_t t[32][33];
  int e0 = blockIdx.x * 32, s0 = blockIdx.y * 32;
  int tx = threadIdx.x, ty = threadIdx.y;
  #pragma unroll
  for (int i = ty; i < 32; i += 8) {
    int s = s0 + i;
    bf16_t v = (bf16_t)0.0f;
    if (s < 196) v = qkv[(long)(b * 196 + s) * 2304 + 1536 + h * 64 + e0 + tx];
    t[i][tx] = v;
  }
  __syncthreads();
  #pragma unroll
  for (int i = ty; i < 32; i += 8) {
    int e = e0 + i, s = s0 + tx;
    if (s < 224) Vt[(long)bh * 64 * 224 + (long)e * 224 + s] = t[tx][i];
  }
}

// ---------------------------------------------------------------------------
// Fused attention: scores -> softmax -> P in LDS -> P@V -> att.
// ---------------------------------------------------------------------------
__global__ __launch_bounds__(64) void attn_fused(
    const bf16_t* __restrict__ qkv, const bf16_t* __restrict__ Vt,
    bf16_t* __restrict__ att)
{
  __shared__ __align__(16) bf16_t Pl[16 * 232];
  int mt = blockIdx.x, bh = blockIdx.y;
  int b = bh / 12, h = bh % 12;
  int lane = threadIdx.x, quad = lane >> 4, l16 = lane & 15;

  #pragma unroll
  for (int i = 0; i < 4; ++i) {
    int idx = lane + 64 * i;
    Pl[(idx >> 4) * 232 + 208 + (idx & 15)] = (bf16_t)0.0f;
  }

  f32x4 zero = {0.f, 0.f, 0.f, 0.f};
  f32x4 acc[13];
  #pragma unroll
  for (int nt = 0; nt < 13; ++nt) acc[nt] = zero;

  long qoff = (long)(b * 196 + mt * 16 + l16) * 2304 + h * 64;
  #pragma unroll
  for (int kk = 0; kk < 2; ++kk) {
    bf16x8 a = *(const bf16x8*)(qkv + qoff + kk * 32 + quad * 8);
    #pragma unroll
    for (int nt = 0; nt < 13; ++nt) {
      long koff = (long)(b * 196 + nt * 16 + l16) * 2304 + 768 + h * 64 + kk * 32 + quad * 8;
      bf16x8 bb = *(const bf16x8*)(qkv + koff);
      acc[nt] = __builtin_amdgcn_mfma_f32_16x16x32_bf16(a, bb, acc[nt], 0, 0, 0);
    }
  }

  float p[13][4];
  #pragma unroll
  for (int nt = 0; nt < 13; ++nt)
    #pragma unroll
    for (int r = 0; r < 4; ++r) {
      float v = acc[nt][r] * 0.125f;
      if (nt == 12 && l16 >= 4) v = -1e30f;
      p[nt][r] = v;
    }

  #pragma unroll
  for (int r = 0; r < 4; ++r) {
    float mx = -1e30f;
    #pragma unroll
    for (int nt = 0; nt < 13; ++nt) mx = fmaxf(mx, p[nt][r]);
    #pragma unroll
    for (int d = 1; d < 16; d <<= 1) mx = fmaxf(mx, __shfl_xor(mx, d, 64));
    float sm = 0.f;
    #pragma unroll
    for (int nt = 0; nt < 13; ++nt) {
      float e = __expf(p[nt][r] - mx);
      p[nt][r] = e;
      sm += e;
    }
    #pragma unroll
    for (int d = 1; d < 16; d <<= 1) sm += __shfl_xor(sm, d, 64);
    float inv = 1.0f / sm;
    #pragma unroll
    for (int nt = 0; nt < 13; ++nt) p[nt][r] *= inv;
  }

  #pragma unroll
  for (int nt = 0; nt < 13; ++nt)
    #pragma unroll
    for (int r = 0; r < 4; ++r)
      Pl[(quad * 4 + r) * 232 + nt * 16 + l16] = (bf16_t)p[nt][r];
  __syncthreads();

  f32x4 pv[4];
  #pragma unroll
  for (int nt = 0; nt < 4; ++nt) pv[nt] = zero;
  const bf16_t* Vb = Vt + (long)bh * 64 * 224;
  #pragma unroll
  for (int ks = 0; ks < 7; ++ks) {
    bf16x8 a = *(const bf16x8*)(Pl + l16 * 232 + ks * 32 + quad * 8);
    #pragma unroll
    for (int nt = 0; nt < 4; ++nt) {
      bf16x8 bb = *(const bf16x8*)(Vb + (long)(nt * 16 + l16) * 224 + ks * 32 + quad * 8);
      pv[nt] = __builtin_amdgcn_mfma_f32_16x16x32_bf16(a, bb, pv[nt], 0, 0, 0);
    }
  }

  #pragma unroll
  for (int nt = 0; nt < 4; ++nt)
    #pragma unroll
    for (int r = 0; r < 4; ++r) {
      int t = mt * 16 + quad * 4 + r;
      if (t < 196)
        att[(long)(b * 196 + t) * 768 + h * 64 + nt * 16 + l16] = (bf16_t)pv[nt][r];
    }
}

// ---------------------------------------------------------------------------
// Mean pool + final MLP2 partial reduction (3 partials) + bias
// ---------------------------------------------------------------------------
__global__ __launch_bounds__(256) void meanpool_fuse(
    const float* __restrict__ h, const bf16_t* __restrict__ pbuf,
    const float* __restrict__ bias, bf16_t* __restrict__ hm)
{
  int d = blockIdx.y * 256 + threadIdx.x;
  int b = blockIdx.x;
  float s = 0.f;
  for (int t = 0; t < 196; ++t) {
    long idx = (long)(b * 196 + t) * 768 + d;
    float v = h[idx];
    #pragma unroll
    for (int pp = 0; pp < 3; ++pp) v += (float)pbuf[idx + pp * PSTRIDE];
    s += v;
  }
  hm[b * 768 + d] = (bf16_t)(s * (1.0f / 196.0f) + bias[d]);
}

// ---------------------------------------------------------------------------
// Host launch
// ---------------------------------------------------------------------------
extern "C" void kernel_launch(void* const* d_in, const int* in_sizes, int n_in,
                              void* d_out, int out_size, void* d_ws, size_t ws_size,
                              hipStream_t stream)
{
  const float* x       = (const float*)d_in[0];
  const float* embed_W = (const float*)d_in[1];
  const float* embed_b = (const float*)d_in[2];
  const float* Wq      = (const float*)d_in[3];
  const float* Wk      = (const float*)d_in[4];
  const float* Wv      = (const float*)d_in[5];
  const float* Wo      = (const float*)d_in[6];
  const float* bo      = (const float*)d_in[7];
  const float* ln1_g   = (const float*)d_in[8];
  const float* ln1_b   = (const float*)d_in[9];
  const float* ln2_g   = (const float*)d_in[10];
  const float* ln2_b   = (const float*)d_in[11];
  const float* W1      = (const float*)d_in[12];
  const float* b1      = (const float*)d_in[13];
  const float* W2      = (const float*)d_in[14];
  const float* b2      = (const float*)d_in[15];
  const float* head_W  = (const float*)d_in[16];

  char* p = (char*)d_ws;
  auto carve = [&](size_t bytes) {
    char* r = p;
    p += (bytes + 255) & ~(size_t)255;
    return r;
  };
  bf16_t* embed_Wt = (bf16_t*)carve(589824ull * 2);
  bf16_t* qkvT     = (bf16_t*)carve(21233664ull * 2);
  bf16_t* WoT      = (bf16_t*)carve(7077888ull * 2);
  bf16_t* W1T      = (bf16_t*)carve(28311552ull * 2);
  bf16_t* W2T      = (bf16_t*)carve(28311552ull * 2);
  bf16_t* headWt   = (bf16_t*)carve(786432ull * 2);
  bf16_t* patches  = (bf16_t*)carve(4816896ull * 2);
  float*  h        = (float*)carve(4816896ull * 4);
  bf16_t* xn       = (bf16_t*)carve(4816896ull * 2);
  bf16_t* qkv      = (bf16_t*)carve(14487552ull * 2);
  bf16_t* Vt       = (bf16_t*)carve(5505024ull * 2);
  bf16_t* hmlp     = (bf16_t*)carve(19267584ull * 2);
  bf16_t* att      = (bf16_t*)carve(4816896ull * 2);
  bf16_t* pbuf     = (bf16_t*)carve(4ull * PSTRIDE * 2);
  bf16_t* hm       = (bf16_t*)carve(98304ull * 2);
  (void)ws_size; (void)n_in; (void)in_sizes; (void)out_size;

  dim3 tb32(32, 8);

  tcvt<<<dim3(24, 24, 1),   tb32, 0, stream>>>(embed_W, embed_Wt, 768, 768, 0, 0, 0, 1);
  tcvt<<<dim3(24, 24, 12),  tb32, 0, stream>>>(Wo, WoT, 768, 768, 589824, 589824, 0, 1);
  tcvt<<<dim3(2, 24, 144),  tb32, 0, stream>>>(Wq, qkvT,           768, 64, 49152, 1769472, 49152, 12);
  tcvt<<<dim3(2, 24, 144),  tb32, 0, stream>>>(Wk, qkvT + 589824,  768, 64, 49152, 1769472, 49152, 12);
  tcvt<<<dim3(2, 24, 144),  tb32, 0, stream>>>(Wv, qkvT + 1179648, 768, 64, 49152, 1769472, 49152, 12);
  tcvt<<<dim3(96, 24, 12),  tb32, 0, stream>>>(W1, W1T, 768, 3072, 2359296, 2359296, 0, 1);
  tcvt<<<dim3(24, 96, 12),  tb32, 0, stream>>>(W2, W2T, 3072, 768, 2359296, 2359296, 0, 1);
  tcvt<<<dim3(32, 24, 1),   tb32, 0, stream>>>(head_W, headWt, 768, 1000, 0, 0, 0, 1);

  patchify<<<18816, 256, 0, stream>>>(x, patches);
  hinit<<<588, 256, 0, stream>>>(embed_b, h);

  gemm_bt<5, 768, 2><<<BMPAD * 6 * 2, 256, 0, stream>>>(
      patches, embed_Wt, 768, 6272, 768, nullptr, nullptr, pbuf);

  for (int l = 0; l < NLAYER; ++l) {
    ln_fuse<<<1568, 256, 0, stream>>>(
        h, pbuf, l == 0 ? 2 : 3, l == 0 ? nullptr : b2 + (l - 1) * 768,
        ln1_g + l * 768, ln1_b + l * 768, xn);
    gemm256<0, 768, 1, 9><<<NBM256 * 9, 512, 0, stream>>>(
        xn, qkvT + (long)l * 1769472, 2304, 6272, nullptr, qkv);
    vtrans<<<dim3(2, 7, 384), tb32, 0, stream>>>(qkv, Vt);
    attn_fused<<<dim3(13, 384), 64, 0, stream>>>(qkv, Vt, att);
    gemm_bt<5, 768, 2><<<BMPAD * 6 * 2, 256, 0, stream>>>(
        att, WoT + (long)l * 589824, 768, 6272, 768,
        nullptr, nullptr, pbuf);
    ln_fuse<<<1568, 256, 0, stream>>>(
        h, pbuf, 2, bo + l * 768, ln2_g + l * 768, ln2_b + l * 768, xn);
    gemm_bt<3, 768, 1><<<BMPAD * 24, 256, 0, stream>>>(
        xn, W1T + (long)l * 2359296, 3072, 6272, 3072,
        b1 + l * 3072, nullptr, hmlp);
    gemm256<5, 3072, 3, 9><<<NBM256 * 9, 512, 0, stream>>>(
        hmlp, W2T + (long)l * 2359296, 768, 6272, nullptr, pbuf);
  }

  meanpool_fuse<<<dim3(32, 3), 256, 0, stream>>>(h, pbuf, b2 + 11 * 768, hm);
  gemm_bt<4, 768, 1><<<BMPAD * 8, 256, 0, stream>>>(
      hm, headWt, 1000, 32, 1000, nullptr, (float*)d_out, nullptr);
}